// Round 7
// baseline (352.479 us; speedup 1.0000x reference)
//
#include <hip/hip_runtime.h>
#include <hip/hip_bf16.h>

constexpr int B = 16, H = 224, W = 224, CI = 3, CO = 64, K = 7;
constexpr int SEG = 196, E = 768;
constexpr int HW = H * W;
constexpr int PP = 201;         // pooled LDS stride
constexpr int EC = 32;          // conv1d e-chunk

constexpr int TSLOTS = 10;      // T ring rows (4 concurrent y + 6 halo)

typedef __attribute__((ext_vector_type(8))) short bf16x8;
typedef __attribute__((ext_vector_type(16))) float f32x16;

__device__ inline unsigned short bfb(float f) {
    union { __hip_bfloat16 h; unsigned short u; } cv; cv.h = __float2bfloat16(f); return cv.u;
}
__device__ inline unsigned pack2(float lo, float hi) {
    return (unsigned)bfb(lo) | ((unsigned)bfb(hi) << 16);
}
__device__ inline float bf2f(unsigned short u) {
    return __uint_as_float(((unsigned)u) << 16);
}

// ---------------- kA: present flags + raw-id histogram ----------------
__global__ void k_count(const int* __restrict__ seg, int* __restrict__ present,
                        unsigned* __restrict__ counts_raw) {
    __shared__ unsigned cnt[SEG];
    const int tid = threadIdx.x, b = blockIdx.y, y0 = blockIdx.x * 8;
    for (int i = tid; i < SEG; i += 256) cnt[i] = 0u;
    __syncthreads();
    for (int i = tid; i < 8 * W; i += 256) {
        int s = seg[b * HW + y0 * W + i];
        present[b * SEG + s] = 1;
        atomicAdd(&cnt[s], 1u);
    }
    __syncthreads();
    for (int i = tid; i < SEG; i += 256)
        if (cnt[i]) atomicAdd(&counts_raw[b * SEG + i], cnt[i]);
}

// ---------------- kB: per-image scans -> rank, offsets, cursors ----------------
__global__ void k_offsets(const int* __restrict__ present,
                          const unsigned* __restrict__ counts_raw,
                          int* __restrict__ rank, int* __restrict__ off_rank,
                          int* __restrict__ cnt_rank, unsigned* __restrict__ cursor) {
    __shared__ int buf[256];
    const int b = blockIdx.x, t = threadIdx.x;
    int pres = (t < SEG) ? present[b * SEG + t] : 0;
    int cv   = (t < SEG) ? (int)counts_raw[b * SEG + t] : 0;
    buf[t] = pres; __syncthreads();
    for (int off = 1; off < 256; off <<= 1) {
        int u = (t >= off) ? buf[t - off] : 0; __syncthreads();
        buf[t] += u; __syncthreads();
    }
    int rk = buf[t] - 1;
    if (t < SEG) rank[b * SEG + t] = rk;
    __syncthreads();
    buf[t] = cv; __syncthreads();
    for (int off = 1; off < 256; off <<= 1) {
        int u = (t >= off) ? buf[t - off] : 0; __syncthreads();
        buf[t] += u; __syncthreads();
    }
    int offx = buf[t] - cv;
    if (t < SEG) {
        cursor[b * SEG + t] = (unsigned)offx;
        cnt_rank[b * SEG + t] = 0;
        off_rank[b * SEG + t] = 0;
    }
    __syncthreads();
    if (t < SEG && pres) {
        cnt_rank[b * SEG + rk] = cv;
        off_rank[b * SEG + rk] = offx;
    }
}

// ---------------- kC: bucket pixel indices per segment + f_segment out ----------------
__global__ void k_scatter(const int* __restrict__ seg, const int* __restrict__ rank,
                          unsigned* __restrict__ cursor, unsigned* __restrict__ bucket,
                          float* __restrict__ out2) {
    __shared__ unsigned bcnt[SEG];
    __shared__ int base_l[SEG];
    __shared__ int rank_lds[SEG];
    __shared__ unsigned char ss[8 * W];
    __shared__ unsigned short lp[8 * W];
    const int tid = threadIdx.x, b = blockIdx.y, y0 = blockIdx.x * 8;
    for (int i = tid; i < SEG; i += 256) { bcnt[i] = 0u; rank_lds[i] = rank[b * SEG + i]; }
    __syncthreads();
    for (int i = tid; i < 8 * W; i += 256) {
        int s = seg[b * HW + y0 * W + i];
        ss[i] = (unsigned char)s;
        out2[b * HW + y0 * W + i] = (float)rank_lds[s];
        lp[i] = (unsigned short)atomicAdd(&bcnt[s], 1u);
    }
    __syncthreads();
    for (int i = tid; i < SEG; i += 256)
        if (bcnt[i]) base_l[i] = (int)atomicAdd(&cursor[b * SEG + i], bcnt[i]);
    __syncthreads();
    for (int i = tid; i < 8 * W; i += 256) {
        int s = ss[i];
        bucket[b * HW + base_l[s] + lp[i]] = (unsigned)(y0 * W + i);
    }
}

// ---------------- k_post: pos [64][HW] f32 -> pos_t [HW][64] bf16, +b1 folded --------
__global__ void k_post(const float* __restrict__ pos, const float* __restrict__ b1,
                       unsigned short* __restrict__ pos_t) {
    const int p = blockIdx.x * 256 + threadIdx.x;
    unsigned d[32];
    #pragma unroll
    for (int c = 0; c < 32; ++c) {
        float v0 = pos[(size_t)(2 * c) * HW + p]     + b1[2 * c];
        float v1 = pos[(size_t)(2 * c + 1) * HW + p] + b1[2 * c + 1];
        d[c] = pack2(v0, v1);
    }
    uint4* op = (uint4*)&pos_t[(size_t)p * 64];
    #pragma unroll
    for (int q = 0; q < 8; ++q) {
        uint4 v = {d[4 * q], d[4 * q + 1], d[4 * q + 2], d[4 * q + 3]};
        op[q] = v;
    }
}

// ---------------- k_wt: pack w1 -> w1t[ky][ks][cg][lane][8] bf16 (frag-contiguous) ----
__global__ void k_wt(const float* __restrict__ w1, unsigned short* __restrict__ w1t) {
    int i = blockIdx.x * 256 + threadIdx.x;
    if (i < 7 * 2 * 2 * 64 * 8) {
        int e = i & 7, lane = (i >> 3) & 63, cg = (i >> 9) & 1, ks = (i >> 10) & 1, ky = i >> 11;
        int kk = ks * 16 + (lane >> 5) * 8 + e;
        int co = cg * 32 + (lane & 31);
        float v = 0.f;
        if (kk < 24) {
            int ci = kk >> 3, kx = kk & 7;
            if (kx < 7) v = w1[((co * 3 + ci) * 7 + ky) * 7 + kx];
        }
        w1t[i] = bfb(v);
    }
}

// ---------------- k_conv_mfma: conv7x7 via bf16 MFMA -> h pixel-major bf16 ------------
// grid (img, 7 x-chunks of 32, 8 y-strips of 28). 4 waves, wave w owns row ys+w.
// T[slot][quad=kk/8][x][8]: A-frag read AND build write are lane-stride-16B (no conflicts).
__launch_bounds__(256, 3)
__global__ void k_conv_mfma(const float* __restrict__ x,
                            const unsigned short* __restrict__ w1t,
                            const unsigned short* __restrict__ pos_t,
                            __hip_bfloat16* __restrict__ h, int b0) {
    __shared__ unsigned short Tl[TSLOTS * 4 * 32 * 8];   // 20480 B

    const int tid = threadIdx.x;
    const int lb  = blockIdx.x;
    const int b   = b0 + lb;
    const int x0  = blockIdx.y * 32;
    const int y0  = blockIdx.z * 28;
    const int lane = tid & 63;
    const int ln31 = lane & 31;
    const int g    = lane >> 5;
    const int wave = tid >> 6;

    // B-fragments straight from global (L2-resident 57KB, coalesced 16B/lane)
    bf16x8 bfr[7][2][2];
    #pragma unroll
    for (int ky = 0; ky < 7; ++ky)
        #pragma unroll
        for (int ks = 0; ks < 2; ++ks)
            #pragma unroll
            for (int cg = 0; cg < 2; ++cg)
                bfr[ky][ks][cg] = *(const bf16x8*)&w1t[((((ky * 2 + ks) * 2 + cg) * 64) + lane) * 8];

    // zero T (pad quad 3 must be 0), then fill rows y0-3 .. y0+6
    for (int i = tid; i < TSLOTS * 4 * 32 * 8; i += 256) Tl[i] = 0;
    __syncthreads();
    for (int idx = tid; idx < 96 * TSLOTS; idx += 256) {
        int jr = idx / 96, rem = idx % 96;
        int ci = rem >> 5, xl = rem & 31;
        int r = y0 - 3 + jr;
        unsigned slot = (unsigned)(r + 3) % TSLOTS;
        uint4 dv = {0, 0, 0, 0};
        if (r >= 0 && r < H) {
            const float* xr = &x[((size_t)(b * CI + ci) * H + r) * W];
            float v[7];
            #pragma unroll
            for (int kx = 0; kx < 7; ++kx) {
                int gx = x0 + xl - 3 + kx;
                v[kx] = (gx >= 0 && gx < W) ? xr[gx] : 0.f;
            }
            dv.x = pack2(v[0], v[1]); dv.y = pack2(v[2], v[3]);
            dv.z = pack2(v[4], v[5]); dv.w = pack2(v[6], 0.f);
        }
        *(uint4*)&Tl[((slot * 4 + ci) * 32 + xl) * 8] = dv;
    }
    __syncthreads();

    for (int s = 0; s < 7; ++s) {
        const int ys = y0 + s * 4;
        const int y  = ys + wave;

        // (a) prefetch next 4 rows' build data into registers (latency hides under MFMA)
        float ld0[7], ld1[7];
        int slot0 = 0, slot1 = 0, ci0 = 0, ci1 = 0, xl0 = 0, xl1 = 0;
        bool act1 = false;
        if (s < 6) {
            {
                int idx = tid;                       // 0..255 < 384: always active
                int jr = idx / 96, rem = idx % 96;
                ci0 = rem >> 5; xl0 = rem & 31;
                int r = ys + 7 + jr;
                slot0 = (int)((unsigned)(r + 3) % TSLOTS);
                #pragma unroll
                for (int kx = 0; kx < 7; ++kx) {
                    int gx = x0 + xl0 - 3 + kx;
                    bool ok = (r < H) && gx >= 0 && gx < W;
                    ld0[kx] = ok ? x[((size_t)(b * CI + ci0) * H + r) * W + gx] : 0.f;
                }
            }
            {
                int idx = tid + 256;
                act1 = idx < 384;
                int jr = idx / 96, rem = idx % 96;
                ci1 = rem >> 5; xl1 = rem & 31;
                int r = ys + 7 + jr;
                slot1 = (int)((unsigned)(r + 3) % TSLOTS);
                #pragma unroll
                for (int kx = 0; kx < 7; ++kx) {
                    int gx = x0 + xl1 - 3 + kx;
                    bool ok = act1 && (r < H) && gx >= 0 && gx < W;
                    ld1[kx] = ok ? x[((size_t)(b * CI + ci1) * H + r) * W + gx] : 0.f;
                }
            }
        }

        // (b) MFMA over 7 ky x 2 ks
        f32x16 c0, c1;
        #pragma unroll
        for (int i = 0; i < 16; ++i) { c0[i] = 0.f; c1[i] = 0.f; }
        int sl = y % TSLOTS;                         // slot of row y-3
        #pragma unroll
        for (int ky = 0; ky < 7; ++ky) {
            const unsigned short* tq = &Tl[sl * (4 * 32 * 8)];
            bf16x8 a0 = *(const bf16x8*)&tq[((0 * 2 + g) * 32 + ln31) * 8];
            bf16x8 a1 = *(const bf16x8*)&tq[((1 * 2 + g) * 32 + ln31) * 8];
            c0 = __builtin_amdgcn_mfma_f32_32x32x16_bf16(a0, bfr[ky][0][0], c0, 0, 0, 0);
            c1 = __builtin_amdgcn_mfma_f32_32x32x16_bf16(a0, bfr[ky][0][1], c1, 0, 0, 0);
            c0 = __builtin_amdgcn_mfma_f32_32x32x16_bf16(a1, bfr[ky][1][0], c0, 0, 0, 0);
            c1 = __builtin_amdgcn_mfma_f32_32x32x16_bf16(a1, bfr[ky][1][1], c1, 0, 0, 0);
            sl = (sl + 1 == TSLOTS) ? 0 : sl + 1;
        }

        // epilogue: C col(co)=ln31, row(px)=(reg&3)+8*(reg>>2)+4*g; pos_t has b1 folded
        #pragma unroll
        for (int reg = 0; reg < 16; ++reg) {
            int pxl = (reg & 3) + 8 * (reg >> 2) + 4 * g;
            int p = y * W + x0 + pxl;
            float pv0 = bf2f(pos_t[(size_t)p * 64 + ln31]);
            float pv1 = bf2f(pos_t[(size_t)p * 64 + 32 + ln31]);
            __hip_bfloat16* hp = &h[((size_t)lb * HW + p) * CO];
            hp[ln31]      = __float2bfloat16(c0[reg] + pv0);
            hp[32 + ln31] = __float2bfloat16(c1[reg] + pv1);
        }

        __syncthreads();
        // (d) commit staged rows to T ring
        if (s < 6) {
            {
                uint4 dv;
                dv.x = pack2(ld0[0], ld0[1]); dv.y = pack2(ld0[2], ld0[3]);
                dv.z = pack2(ld0[4], ld0[5]); dv.w = pack2(ld0[6], 0.f);
                *(uint4*)&Tl[((slot0 * 4 + ci0) * 32 + xl0) * 8] = dv;
            }
            if (act1) {
                uint4 dv;
                dv.x = pack2(ld1[0], ld1[1]); dv.y = pack2(ld1[2], ld1[3]);
                dv.z = pack2(ld1[4], ld1[5]); dv.w = pack2(ld1[6], 0.f);
                *(uint4*)&Tl[((slot1 * 4 + ci1) * 32 + xl1) * 8] = dv;
            }
        }
        __syncthreads();
    }
}

// ---------------- kD: gather-reduce per (image, rank) -> pooled mean ----------------
__global__ void k_gather(const __hip_bfloat16* __restrict__ h,
                         const unsigned* __restrict__ bucket,
                         const int* __restrict__ off_rank,
                         const int* __restrict__ cnt_rank,
                         float* __restrict__ pooled, int b0) {
    const int tid = threadIdx.x;
    const int wave = tid >> 6, lane = tid & 63;
    const int r = blockIdx.x * 4 + wave;
    const int lb = blockIdx.y, b = b0 + lb;
    const int n = cnt_rank[b * SEG + r];
    const int base = off_rank[b * SEG + r];
    const int ps = lane >> 3, cg = lane & 7;

    float acc[8] = {0.f, 0.f, 0.f, 0.f, 0.f, 0.f, 0.f, 0.f};
    const unsigned* bk = &bucket[b * HW + base];
    const int iters = (n + 7) >> 3;
    for (int i = 0; i < iters; ++i) {
        int idx = i * 8 + ps;
        if (idx < n) {
            unsigned p = bk[idx];
            uint4 u = *(const uint4*)&h[((size_t)lb * HW + p) * CO + cg * 8];
            acc[0] += __uint_as_float((u.x & 0xffffu) << 16);
            acc[1] += __uint_as_float(u.x & 0xffff0000u);
            acc[2] += __uint_as_float((u.y & 0xffffu) << 16);
            acc[3] += __uint_as_float(u.y & 0xffff0000u);
            acc[4] += __uint_as_float((u.z & 0xffffu) << 16);
            acc[5] += __uint_as_float(u.z & 0xffff0000u);
            acc[6] += __uint_as_float((u.w & 0xffffu) << 16);
            acc[7] += __uint_as_float(u.w & 0xffff0000u);
        }
    }
    #pragma unroll
    for (int m = 8; m < 64; m <<= 1)
        #pragma unroll
        for (int j = 0; j < 8; ++j) acc[j] += __shfl_xor(acc[j], m, 64);

    if (ps == 0) {
        float inv = (n > 0) ? 1.f / (float)n : 0.f;
        float* op = &pooled[((size_t)b * SEG + r) * CO + cg * 8];
        float4 v0 = {acc[0] * inv, acc[1] * inv, acc[2] * inv, acc[3] * inv};
        float4 v1 = {acc[4] * inv, acc[5] * inv, acc[6] * inv, acc[7] * inv};
        *(float4*)&op[0] = v0;
        *(float4*)&op[4] = v1;
    }
}

// ---------------- kE: conv1d k=3 over pooled -> out ----------------
__launch_bounds__(256, 2)
__global__ void k_pool_conv1d(const float* __restrict__ pooledg,
                              const float* __restrict__ w2,
                              const float* __restrict__ b2,
                              float* __restrict__ out0) {
    __shared__ float pooled[CO * PP];
    __shared__ float w2l[192 * (EC + 1)];
    const int tid = threadIdx.x;
    const int b  = blockIdx.y;
    const int e0 = blockIdx.x * EC;

    for (int i = tid; i < SEG * CO; i += 256) {
        int s = i >> 6, c = i & 63;
        pooled[c * PP + s + 1] = pooledg[((size_t)b * SEG + s) * CO + c];
    }
    for (int i = tid; i < CO * 5; i += 256) {
        int c = i / 5, hh = i % 5;
        pooled[c * PP + (hh == 0 ? 0 : 196 + hh)] = 0.f;
    }
    for (int i = tid; i < EC * 192; i += 256) {
        int e = i / 192, k = i % 192;
        w2l[k * (EC + 1) + e] = w2[(size_t)(e0 + e) * 192 + k];
    }
    __syncthreads();

    const int txs = tid & 31;
    const int te  = tid >> 5;
    const int s0  = txs * 7;
    float acc[7][4];
    #pragma unroll
    for (int ss = 0; ss < 7; ++ss)
        #pragma unroll
        for (int ee = 0; ee < 4; ++ee) acc[ss][ee] = b2[e0 + te * 4 + ee];

    if (s0 < SEG) {
        #pragma unroll 4
        for (int c = 0; c < CO; ++c) {
            float pv[9];
            #pragma unroll
            for (int j = 0; j < 9; ++j) pv[j] = pooled[c * PP + s0 + j];
            #pragma unroll
            for (int dk = 0; dk < 3; ++dk) {
                float wv[4];
                #pragma unroll
                for (int ee = 0; ee < 4; ++ee)
                    wv[ee] = w2l[(c * 3 + dk) * (EC + 1) + te * 4 + ee];
                #pragma unroll
                for (int ss = 0; ss < 7; ++ss)
                    #pragma unroll
                    for (int ee = 0; ee < 4; ++ee)
                        acc[ss][ee] = fmaf(pv[ss + dk], wv[ee], acc[ss][ee]);
            }
        }
        #pragma unroll
        for (int ss = 0; ss < 7; ++ss) {
            int s = s0 + ss;
            float* op = &out0[((size_t)(b * SEG + s) * E) + e0 + te * 4];
            float4 v0 = {acc[ss][0], acc[ss][1], acc[ss][2], acc[ss][3]};
            *(float4*)op = v0;
        }
    }
}

extern "C" void kernel_launch(void* const* d_in, const int* in_sizes, int n_in,
                              void* d_out, int out_size, void* d_ws, size_t ws_size,
                              hipStream_t stream) {
    const float* x   = (const float*)d_in[0];
    const int*   seg = (const int*)d_in[1];
    const float* w1  = (const float*)d_in[2];
    const float* b1  = (const float*)d_in[3];
    const float* pos = (const float*)d_in[4];
    const float* w2  = (const float*)d_in[5];
    const float* b2  = (const float*)d_in[6];

    float* out0 = (float*)d_out;                 // [B,196,768]
    float* out2 = out0 + (size_t)B * SEG * E;    // f_segment as float [B,1,224,224]

    int*      present    = (int*)d_ws;                        // B*SEG [zeroed]
    unsigned* counts_raw = (unsigned*)(present + B * SEG);    // B*SEG [zeroed]
    int*      rank       = (int*)(counts_raw + B * SEG);
    int*      off_rank   = rank + B * SEG;
    int*      cnt_rank   = off_rank + B * SEG;
    unsigned* cursor     = (unsigned*)(cnt_rank + B * SEG);
    float*    pooled     = (float*)(cursor + B * SEG);                  // B*SEG*CO
    unsigned* bucket     = (unsigned*)(pooled + (size_t)B * SEG * CO);  // B*HW
    unsigned short* pos_t = (unsigned short*)(bucket + (size_t)B * HW); // HW*64 bf16
    unsigned short* w1t  = pos_t + (size_t)HW * CO;                     // 28672 bf16
    __hip_bfloat16* hbuf = (__hip_bfloat16*)(w1t + 7 * 2 * 2 * 64 * 8);

    hipMemsetAsync(d_ws, 0, (size_t)2 * B * SEG * 4, stream);

    k_post   <<<dim3(HW / 256), 256, 0, stream>>>(pos, b1, pos_t);
    k_wt     <<<dim3(56),       256, 0, stream>>>(w1, w1t);
    k_count  <<<dim3(28, B), 256, 0, stream>>>(seg, present, counts_raw);
    k_offsets<<<dim3(B),     256, 0, stream>>>(present, counts_raw, rank, off_rank, cnt_rank, cursor);
    k_scatter<<<dim3(28, B), 256, 0, stream>>>(seg, rank, cursor, bucket, out2);

    size_t used = (char*)hbuf - (char*)d_ws;
    size_t h_per_img = (size_t)HW * CO * sizeof(__hip_bfloat16);  // 6.42 MB
    size_t avail = (ws_size > used) ? ws_size - used : 0;
    int ipc = (int)(avail / h_per_img);
    if (ipc < 1) ipc = 1;
    if (ipc > B) ipc = B;

    for (int b0 = 0; b0 < B; b0 += ipc) {
        int nb = (b0 + ipc <= B) ? ipc : (B - b0);
        k_conv_mfma<<<dim3(nb, 7, 8), 256, 0, stream>>>(x, w1t, pos_t, hbuf, b0);
        k_gather   <<<dim3(49, nb),   256, 0, stream>>>(hbuf, bucket, off_rank, cnt_rank, pooled, b0);
    }
    k_pool_conv1d<<<dim3(24, B), 256, 0, stream>>>(pooled, w2, b2, out0);
}

// Round 10
// 275.413 us; speedup vs baseline: 1.2798x; 1.2798x over previous
//
#include <hip/hip_runtime.h>
#include <hip/hip_bf16.h>

constexpr int B = 16, H = 224, W = 224, CI = 3, CO = 64, K = 7;
constexpr int SEG = 196, E = 768;
constexpr int HW = H * W;
constexpr int PP = 201;         // pooled LDS stride
constexpr int EC = 32;          // conv1d e-chunk

constexpr int TSLOTS = 10;      // T ring rows (4 concurrent y + 6 halo)

typedef __attribute__((ext_vector_type(8))) short bf16x8;
typedef __attribute__((ext_vector_type(16))) float f32x16;

__device__ inline unsigned short bfb(float f) {
    union { __hip_bfloat16 h; unsigned short u; } cv; cv.h = __float2bfloat16(f); return cv.u;
}
__device__ inline unsigned pack2(float lo, float hi) {
    return (unsigned)bfb(lo) | ((unsigned)bfb(hi) << 16);
}
__device__ inline float bf2f(unsigned short u) {
    return __uint_as_float(((unsigned)u) << 16);
}

// ---------------- kA: present flags + raw-id histogram ----------------
__global__ void k_count(const int* __restrict__ seg, int* __restrict__ present,
                        unsigned* __restrict__ counts_raw) {
    __shared__ unsigned cnt[SEG];
    const int tid = threadIdx.x, b = blockIdx.y, y0 = blockIdx.x * 8;
    for (int i = tid; i < SEG; i += 256) cnt[i] = 0u;
    __syncthreads();
    for (int i = tid; i < 8 * W; i += 256) {
        int s = seg[b * HW + y0 * W + i];
        present[b * SEG + s] = 1;
        atomicAdd(&cnt[s], 1u);
    }
    __syncthreads();
    for (int i = tid; i < SEG; i += 256)
        if (cnt[i]) atomicAdd(&counts_raw[b * SEG + i], cnt[i]);
}

// ---------------- kB: per-image scans -> rank, offsets, cursors ----------------
__global__ void k_offsets(const int* __restrict__ present,
                          const unsigned* __restrict__ counts_raw,
                          int* __restrict__ rank, int* __restrict__ off_rank,
                          int* __restrict__ cnt_rank, unsigned* __restrict__ cursor) {
    __shared__ int buf[256];
    const int b = blockIdx.x, t = threadIdx.x;
    int pres = (t < SEG) ? present[b * SEG + t] : 0;
    int cv   = (t < SEG) ? (int)counts_raw[b * SEG + t] : 0;
    buf[t] = pres; __syncthreads();
    for (int off = 1; off < 256; off <<= 1) {
        int u = (t >= off) ? buf[t - off] : 0; __syncthreads();
        buf[t] += u; __syncthreads();
    }
    int rk = buf[t] - 1;
    if (t < SEG) rank[b * SEG + t] = rk;
    __syncthreads();
    buf[t] = cv; __syncthreads();
    for (int off = 1; off < 256; off <<= 1) {
        int u = (t >= off) ? buf[t - off] : 0; __syncthreads();
        buf[t] += u; __syncthreads();
    }
    int offx = buf[t] - cv;
    if (t < SEG) {
        cursor[b * SEG + t] = (unsigned)offx;
        cnt_rank[b * SEG + t] = 0;
        off_rank[b * SEG + t] = 0;
    }
    __syncthreads();
    if (t < SEG && pres) {
        cnt_rank[b * SEG + rk] = cv;
        off_rank[b * SEG + rk] = offx;
    }
}

// ---------------- kC: bucket pixel indices per segment + f_segment out ----------------
__global__ void k_scatter(const int* __restrict__ seg, const int* __restrict__ rank,
                          unsigned* __restrict__ cursor, unsigned* __restrict__ bucket,
                          float* __restrict__ out2) {
    __shared__ unsigned bcnt[SEG];
    __shared__ int base_l[SEG];
    __shared__ int rank_lds[SEG];
    __shared__ unsigned char ss[8 * W];
    __shared__ unsigned short lp[8 * W];
    const int tid = threadIdx.x, b = blockIdx.y, y0 = blockIdx.x * 8;
    for (int i = tid; i < SEG; i += 256) { bcnt[i] = 0u; rank_lds[i] = rank[b * SEG + i]; }
    __syncthreads();
    for (int i = tid; i < 8 * W; i += 256) {
        int s = seg[b * HW + y0 * W + i];
        ss[i] = (unsigned char)s;
        out2[b * HW + y0 * W + i] = (float)rank_lds[s];
        lp[i] = (unsigned short)atomicAdd(&bcnt[s], 1u);
    }
    __syncthreads();
    for (int i = tid; i < SEG; i += 256)
        if (bcnt[i]) base_l[i] = (int)atomicAdd(&cursor[b * SEG + i], bcnt[i]);
    __syncthreads();
    for (int i = tid; i < 8 * W; i += 256) {
        int s = ss[i];
        bucket[b * HW + base_l[s] + lp[i]] = (unsigned)(y0 * W + i);
    }
}

// ---------------- k_post: pos [64][HW] f32 -> pos_t [HW][64] bf16, +b1 folded --------
__global__ void k_post(const float* __restrict__ pos, const float* __restrict__ b1,
                       unsigned short* __restrict__ pos_t) {
    const int p = blockIdx.x * 256 + threadIdx.x;
    unsigned d[32];
    #pragma unroll
    for (int c = 0; c < 32; ++c) {
        float v0 = pos[(size_t)(2 * c) * HW + p]     + b1[2 * c];
        float v1 = pos[(size_t)(2 * c + 1) * HW + p] + b1[2 * c + 1];
        d[c] = pack2(v0, v1);
    }
    uint4* op = (uint4*)&pos_t[(size_t)p * 64];
    #pragma unroll
    for (int q = 0; q < 8; ++q) {
        uint4 v = {d[4 * q], d[4 * q + 1], d[4 * q + 2], d[4 * q + 3]};
        op[q] = v;
    }
}

// ---------------- k_wt: pack w1 -> w1t[ky][ks][cg][lane][8] bf16 (frag-contiguous) ----
__global__ void k_wt(const float* __restrict__ w1, unsigned short* __restrict__ w1t) {
    int i = blockIdx.x * 256 + threadIdx.x;
    if (i < 7 * 2 * 2 * 64 * 8) {
        int e = i & 7, lane = (i >> 3) & 63, cg = (i >> 9) & 1, ks = (i >> 10) & 1, ky = i >> 11;
        int kk = ks * 16 + (lane >> 5) * 8 + e;
        int co = cg * 32 + (lane & 31);
        float v = 0.f;
        if (kk < 24) {
            int ci = kk >> 3, kx = kk & 7;
            if (kx < 7) v = w1[((co * 3 + ci) * 7 + ky) * 7 + kx];
        }
        w1t[i] = bfb(v);
    }
}

// ---------------- k_conv_mfma: conv7x7 via bf16 MFMA -> h pixel-major bf16 ------------
// grid (img, 7 x-chunks of 32, 8 y-strips of 28). 4 waves: wave w owns rows
// ys+2*(w>>1)+{0,1}, cg=w&1 -> only 14 B-frags/wave (56 VGPR), no spill.
// T[slot][quad=kk/8][x][8]: A-frag read AND build write lane-stride-16B (conflict-free).
__launch_bounds__(256, 3)
__global__ void k_conv_mfma(const float* __restrict__ x,
                            const unsigned short* __restrict__ w1t,
                            const unsigned short* __restrict__ pos_t,
                            __hip_bfloat16* __restrict__ h, int b0) {
    __shared__ unsigned short Tl[TSLOTS * 4 * 32 * 8];   // 20480 B

    const int tid = threadIdx.x;
    const int lb  = blockIdx.x;
    const int b   = b0 + lb;
    const int x0  = blockIdx.y * 32;
    const int y0  = blockIdx.z * 28;
    const int lane = tid & 63;
    const int ln31 = lane & 31;
    const int g    = lane >> 5;
    const int wave = tid >> 6;
    const int wr   = wave >> 1;      // row-pair index (0,1)
    const int cg   = wave & 1;       // channel group

    // this wave's cg B-fragments from global (L2-resident, coalesced 16B/lane)
    bf16x8 bfr[7][2];
    #pragma unroll
    for (int ky = 0; ky < 7; ++ky)
        #pragma unroll
        for (int ks = 0; ks < 2; ++ks)
            bfr[ky][ks] = *(const bf16x8*)&w1t[((((ky * 2 + ks) * 2 + cg) * 64) + lane) * 8];

    // zero T (pad quad 3 must stay 0), then fill rows y0-3 .. y0+6
    for (int i = tid; i < TSLOTS * 4 * 32 * 8; i += 256) Tl[i] = 0;
    __syncthreads();
    for (int idx = tid; idx < 96 * TSLOTS; idx += 256) {
        int jr = idx / 96, rem = idx % 96;
        int ci = rem >> 5, xl = rem & 31;
        int r = y0 - 3 + jr;
        unsigned slot = (unsigned)(r + 3) % TSLOTS;
        uint4 dv = {0, 0, 0, 0};
        if (r >= 0 && r < H) {
            const float* xr = &x[((size_t)(b * CI + ci) * H + r) * W];
            float v[7];
            #pragma unroll
            for (int kx = 0; kx < 7; ++kx) {
                int gx = x0 + xl - 3 + kx;
                v[kx] = (gx >= 0 && gx < W) ? xr[gx] : 0.f;
            }
            dv.x = pack2(v[0], v[1]); dv.y = pack2(v[2], v[3]);
            dv.z = pack2(v[4], v[5]); dv.w = pack2(v[6], 0.f);
        }
        *(uint4*)&Tl[((slot * 4 + ci) * 32 + xl) * 8] = dv;
    }
    __syncthreads();

    for (int s = 0; s < 7; ++s) {
        const int ys = y0 + s * 4;
        const int row0 = ys + wr * 2;

        // (a) prefetch next 4 rows' build data into registers
        float ld0[7], ld1[7];
        int slot0 = 0, slot1 = 0, ci0 = 0, ci1 = 0, xl0 = 0, xl1 = 0;
        bool act1 = false;
        if (s < 6) {
            {
                int idx = tid;                       // < 384: always active
                int jr = idx / 96, rem = idx % 96;
                ci0 = rem >> 5; xl0 = rem & 31;
                int r = ys + 7 + jr;
                slot0 = (int)((unsigned)(r + 3) % TSLOTS);
                #pragma unroll
                for (int kx = 0; kx < 7; ++kx) {
                    int gx = x0 + xl0 - 3 + kx;
                    bool ok = (r < H) && gx >= 0 && gx < W;
                    ld0[kx] = ok ? x[((size_t)(b * CI + ci0) * H + r) * W + gx] : 0.f;
                }
            }
            {
                int idx = tid + 256;
                act1 = idx < 384;
                int jr = idx / 96, rem = idx % 96;
                ci1 = rem >> 5; xl1 = rem & 31;
                int r = ys + 7 + jr;
                slot1 = (int)((unsigned)(r + 3) % TSLOTS);
                #pragma unroll
                for (int kx = 0; kx < 7; ++kx) {
                    int gx = x0 + xl1 - 3 + kx;
                    bool ok = act1 && (r < H) && gx >= 0 && gx < W;
                    ld1[kx] = ok ? x[((size_t)(b * CI + ci1) * H + r) * W + gx] : 0.f;
                }
            }
        }

        // (b) MFMA: 2 rows x 7 ky x 2 ks (A per row, shared bfr)
        f32x16 c0, c1;
        #pragma unroll
        for (int i = 0; i < 16; ++i) { c0[i] = 0.f; c1[i] = 0.f; }
        int sl = row0 % TSLOTS;                      // slot of row row0-3 (+3)%10
        #pragma unroll
        for (int ky = 0; ky < 7; ++ky) {
            const unsigned short* tq0 = &Tl[sl * (4 * 32 * 8)];
            int sl1 = (sl + 1 == TSLOTS) ? 0 : sl + 1;
            const unsigned short* tq1 = &Tl[sl1 * (4 * 32 * 8)];
            #pragma unroll
            for (int ks = 0; ks < 2; ++ks) {
                bf16x8 a0 = *(const bf16x8*)&tq0[((ks * 2 + g) * 32 + ln31) * 8];
                bf16x8 a1 = *(const bf16x8*)&tq1[((ks * 2 + g) * 32 + ln31) * 8];
                c0 = __builtin_amdgcn_mfma_f32_32x32x16_bf16(a0, bfr[ky][ks], c0, 0, 0, 0);
                c1 = __builtin_amdgcn_mfma_f32_32x32x16_bf16(a1, bfr[ky][ks], c1, 0, 0, 0);
            }
            sl = sl1;
        }

        // epilogue: C col(co)=ln31 (+cg*32), row(px)=(reg&3)+8*(reg>>2)+4*g
        #pragma unroll
        for (int reg = 0; reg < 16; ++reg) {
            int pxl = (reg & 3) + 8 * (reg >> 2) + 4 * g;
            int p0 = row0 * W + x0 + pxl;
            int p1 = p0 + W;
            float pv0 = bf2f(pos_t[(size_t)p0 * 64 + cg * 32 + ln31]);
            float pv1 = bf2f(pos_t[(size_t)p1 * 64 + cg * 32 + ln31]);
            h[((size_t)lb * HW + p0) * CO + cg * 32 + ln31] = __float2bfloat16(c0[reg] + pv0);
            h[((size_t)lb * HW + p1) * CO + cg * 32 + ln31] = __float2bfloat16(c1[reg] + pv1);
        }

        __syncthreads();
        // (d) commit staged rows to T ring
        if (s < 6) {
            {
                uint4 dv;
                dv.x = pack2(ld0[0], ld0[1]); dv.y = pack2(ld0[2], ld0[3]);
                dv.z = pack2(ld0[4], ld0[5]); dv.w = pack2(ld0[6], 0.f);
                *(uint4*)&Tl[((slot0 * 4 + ci0) * 32 + xl0) * 8] = dv;
            }
            if (act1) {
                uint4 dv;
                dv.x = pack2(ld1[0], ld1[1]); dv.y = pack2(ld1[2], ld1[3]);
                dv.z = pack2(ld1[4], ld1[5]); dv.w = pack2(ld1[6], 0.f);
                *(uint4*)&Tl[((slot1 * 4 + ci1) * 32 + xl1) * 8] = dv;
            }
        }
        __syncthreads();
    }
}

// ---------------- kD: gather-reduce per (image, rank) -> pooled mean ----------------
__global__ void k_gather(const __hip_bfloat16* __restrict__ h,
                         const unsigned* __restrict__ bucket,
                         const int* __restrict__ off_rank,
                         const int* __restrict__ cnt_rank,
                         float* __restrict__ pooled, int b0) {
    const int tid = threadIdx.x;
    const int wave = tid >> 6, lane = tid & 63;
    const int r = blockIdx.x * 4 + wave;
    const int lb = blockIdx.y, b = b0 + lb;
    const int n = cnt_rank[b * SEG + r];
    const int base = off_rank[b * SEG + r];
    const int ps = lane >> 3, cg = lane & 7;

    float acc[8] = {0.f, 0.f, 0.f, 0.f, 0.f, 0.f, 0.f, 0.f};
    const unsigned* bk = &bucket[b * HW + base];
    const int iters = (n + 7) >> 3;
    for (int i = 0; i < iters; ++i) {
        int idx = i * 8 + ps;
        if (idx < n) {
            unsigned p = bk[idx];
            uint4 u = *(const uint4*)&h[((size_t)lb * HW + p) * CO + cg * 8];
            acc[0] += __uint_as_float((u.x & 0xffffu) << 16);
            acc[1] += __uint_as_float(u.x & 0xffff0000u);
            acc[2] += __uint_as_float((u.y & 0xffffu) << 16);
            acc[3] += __uint_as_float(u.y & 0xffff0000u);
            acc[4] += __uint_as_float((u.z & 0xffffu) << 16);
            acc[5] += __uint_as_float(u.z & 0xffff0000u);
            acc[6] += __uint_as_float((u.w & 0xffffu) << 16);
            acc[7] += __uint_as_float(u.w & 0xffff0000u);
        }
    }
    #pragma unroll
    for (int m = 8; m < 64; m <<= 1)
        #pragma unroll
        for (int j = 0; j < 8; ++j) acc[j] += __shfl_xor(acc[j], m, 64);

    if (ps == 0) {
        float inv = (n > 0) ? 1.f / (float)n : 0.f;
        float* op = &pooled[((size_t)b * SEG + r) * CO + cg * 8];
        float4 v0 = {acc[0] * inv, acc[1] * inv, acc[2] * inv, acc[3] * inv};
        float4 v1 = {acc[4] * inv, acc[5] * inv, acc[6] * inv, acc[7] * inv};
        *(float4*)&op[0] = v0;
        *(float4*)&op[4] = v1;
    }
}

// ---------------- kE: conv1d k=3 over pooled -> out ----------------
__launch_bounds__(256, 2)
__global__ void k_pool_conv1d(const float* __restrict__ pooledg,
                              const float* __restrict__ w2,
                              const float* __restrict__ b2,
                              float* __restrict__ out0) {
    __shared__ float pooled[CO * PP];
    __shared__ float w2l[192 * (EC + 1)];
    const int tid = threadIdx.x;
    const int b  = blockIdx.y;
    const int e0 = blockIdx.x * EC;

    for (int i = tid; i < SEG * CO; i += 256) {
        int s = i >> 6, c = i & 63;
        pooled[c * PP + s + 1] = pooledg[((size_t)b * SEG + s) * CO + c];
    }
    for (int i = tid; i < CO * 5; i += 256) {
        int c = i / 5, hh = i % 5;
        pooled[c * PP + (hh == 0 ? 0 : 196 + hh)] = 0.f;
    }
    for (int i = tid; i < EC * 192; i += 256) {
        int e = i / 192, k = i % 192;
        w2l[k * (EC + 1) + e] = w2[(size_t)(e0 + e) * 192 + k];
    }
    __syncthreads();

    const int txs = tid & 31;
    const int te  = tid >> 5;
    const int s0  = txs * 7;
    float acc[7][4];
    #pragma unroll
    for (int ss = 0; ss < 7; ++ss)
        #pragma unroll
        for (int ee = 0; ee < 4; ++ee) acc[ss][ee] = b2[e0 + te * 4 + ee];

    if (s0 < SEG) {
        #pragma unroll 4
        for (int c = 0; c < CO; ++c) {
            float pv[9];
            #pragma unroll
            for (int j = 0; j < 9; ++j) pv[j] = pooled[c * PP + s0 + j];
            #pragma unroll
            for (int dk = 0; dk < 3; ++dk) {
                float wv[4];
                #pragma unroll
                for (int ee = 0; ee < 4; ++ee)
                    wv[ee] = w2l[(c * 3 + dk) * (EC + 1) + te * 4 + ee];
                #pragma unroll
                for (int ss = 0; ss < 7; ++ss)
                    #pragma unroll
                    for (int ee = 0; ee < 4; ++ee)
                        acc[ss][ee] = fmaf(pv[ss + dk], wv[ee], acc[ss][ee]);
            }
        }
        #pragma unroll
        for (int ss = 0; ss < 7; ++ss) {
            int s = s0 + ss;
            float* op = &out0[((size_t)(b * SEG + s) * E) + e0 + te * 4];
            float4 v0 = {acc[ss][0], acc[ss][1], acc[ss][2], acc[ss][3]};
            *(float4*)op = v0;
        }
    }
}

extern "C" void kernel_launch(void* const* d_in, const int* in_sizes, int n_in,
                              void* d_out, int out_size, void* d_ws, size_t ws_size,
                              hipStream_t stream) {
    const float* x   = (const float*)d_in[0];
    const int*   seg = (const int*)d_in[1];
    const float* w1  = (const float*)d_in[2];
    const float* b1  = (const float*)d_in[3];
    const float* pos = (const float*)d_in[4];
    const float* w2  = (const float*)d_in[5];
    const float* b2  = (const float*)d_in[6];

    float* out0 = (float*)d_out;                 // [B,196,768]
    float* out2 = out0 + (size_t)B * SEG * E;    // f_segment as float [B,1,224,224]

    int*      present    = (int*)d_ws;                        // B*SEG [zeroed]
    unsigned* counts_raw = (unsigned*)(present + B * SEG);    // B*SEG [zeroed]
    int*      rank       = (int*)(counts_raw + B * SEG);
    int*      off_rank   = rank + B * SEG;
    int*      cnt_rank   = off_rank + B * SEG;
    unsigned* cursor     = (unsigned*)(cnt_rank + B * SEG);
    float*    pooled     = (float*)(cursor + B * SEG);                  // B*SEG*CO
    unsigned* bucket     = (unsigned*)(pooled + (size_t)B * SEG * CO);  // B*HW
    unsigned short* pos_t = (unsigned short*)(bucket + (size_t)B * HW); // HW*64 bf16
    unsigned short* w1t  = pos_t + (size_t)HW * CO;                     // 28672 bf16
    __hip_bfloat16* hbuf = (__hip_bfloat16*)(w1t + 7 * 2 * 2 * 64 * 8);

    hipMemsetAsync(d_ws, 0, (size_t)2 * B * SEG * 4, stream);

    k_post   <<<dim3(HW / 256), 256, 0, stream>>>(pos, b1, pos_t);
    k_wt     <<<dim3(56),       256, 0, stream>>>(w1, w1t);
    k_count  <<<dim3(28, B), 256, 0, stream>>>(seg, present, counts_raw);
    k_offsets<<<dim3(B),     256, 0, stream>>>(present, counts_raw, rank, off_rank, cnt_rank, cursor);
    k_scatter<<<dim3(28, B), 256, 0, stream>>>(seg, rank, cursor, bucket, out2);

    size_t used = (char*)hbuf - (char*)d_ws;
    size_t h_per_img = (size_t)HW * CO * sizeof(__hip_bfloat16);  // 6.42 MB
    size_t avail = (ws_size > used) ? ws_size - used : 0;
    int ipc = (int)(avail / h_per_img);
    if (ipc < 1) ipc = 1;
    if (ipc > B) ipc = B;

    for (int b0 = 0; b0 < B; b0 += ipc) {
        int nb = (b0 + ipc <= B) ? ipc : (B - b0);
        k_conv_mfma<<<dim3(nb, 7, 8), 256, 0, stream>>>(x, w1t, pos_t, hbuf, b0);
        k_gather   <<<dim3(49, nb),   256, 0, stream>>>(hbuf, bucket, off_rank, cnt_rank, pooled, b0);
    }
    k_pool_conv1d<<<dim3(24, B), 256, 0, stream>>>(pooled, w2, b2, out0);
}

// Round 12
// 220.780 us; speedup vs baseline: 1.5965x; 1.2475x over previous
//
#include <hip/hip_runtime.h>
#include <hip/hip_bf16.h>

constexpr int B = 16, H = 224, W = 224, CI = 3, CO = 64, K = 7;
constexpr int SEG = 196, E = 768;
constexpr int HW = H * W;
constexpr int PP = 201;         // pooled LDS stride
constexpr int EC = 32;          // conv1d e-chunk

constexpr int TSLOTS = 10;      // 4 output rows + 6 halo, all resident (no ring)

typedef __attribute__((ext_vector_type(8))) short bf16x8;
typedef __attribute__((ext_vector_type(16))) float f32x16;

__device__ inline unsigned short bfb(float f) {
    union { __hip_bfloat16 h; unsigned short u; } cv; cv.h = __float2bfloat16(f); return cv.u;
}
__device__ inline unsigned pack2(float lo, float hi) {
    return (unsigned)bfb(lo) | ((unsigned)bfb(hi) << 16);
}
__device__ inline float bf2f(unsigned short u) {
    return __uint_as_float(((unsigned)u) << 16);
}

// ---------------- kA: present flags + raw-id histogram ----------------
__global__ void k_count(const int* __restrict__ seg, int* __restrict__ present,
                        unsigned* __restrict__ counts_raw) {
    __shared__ unsigned cnt[SEG];
    const int tid = threadIdx.x, b = blockIdx.y, y0 = blockIdx.x * 8;
    for (int i = tid; i < SEG; i += 256) cnt[i] = 0u;
    __syncthreads();
    for (int i = tid; i < 8 * W; i += 256) {
        int s = seg[b * HW + y0 * W + i];
        present[b * SEG + s] = 1;
        atomicAdd(&cnt[s], 1u);
    }
    __syncthreads();
    for (int i = tid; i < SEG; i += 256)
        if (cnt[i]) atomicAdd(&counts_raw[b * SEG + i], cnt[i]);
}

// ---------------- kB: per-image scans -> rank, offsets, cursors ----------------
__global__ void k_offsets(const int* __restrict__ present,
                          const unsigned* __restrict__ counts_raw,
                          int* __restrict__ rank, int* __restrict__ off_rank,
                          int* __restrict__ cnt_rank, unsigned* __restrict__ cursor) {
    __shared__ int buf[256];
    const int b = blockIdx.x, t = threadIdx.x;
    int pres = (t < SEG) ? present[b * SEG + t] : 0;
    int cv   = (t < SEG) ? (int)counts_raw[b * SEG + t] : 0;
    buf[t] = pres; __syncthreads();
    for (int off = 1; off < 256; off <<= 1) {
        int u = (t >= off) ? buf[t - off] : 0; __syncthreads();
        buf[t] += u; __syncthreads();
    }
    int rk = buf[t] - 1;
    if (t < SEG) rank[b * SEG + t] = rk;
    __syncthreads();
    buf[t] = cv; __syncthreads();
    for (int off = 1; off < 256; off <<= 1) {
        int u = (t >= off) ? buf[t - off] : 0; __syncthreads();
        buf[t] += u; __syncthreads();
    }
    int offx = buf[t] - cv;
    if (t < SEG) {
        cursor[b * SEG + t] = (unsigned)offx;
        cnt_rank[b * SEG + t] = 0;
        off_rank[b * SEG + t] = 0;
    }
    __syncthreads();
    if (t < SEG && pres) {
        cnt_rank[b * SEG + rk] = cv;
        off_rank[b * SEG + rk] = offx;
    }
}

// ---------------- kC: bucket pixel indices per segment + f_segment out ----------------
__global__ void k_scatter(const int* __restrict__ seg, const int* __restrict__ rank,
                          unsigned* __restrict__ cursor, unsigned* __restrict__ bucket,
                          float* __restrict__ out2) {
    __shared__ unsigned bcnt[SEG];
    __shared__ int base_l[SEG];
    __shared__ int rank_lds[SEG];
    __shared__ unsigned char ss[8 * W];
    __shared__ unsigned short lp[8 * W];
    const int tid = threadIdx.x, b = blockIdx.y, y0 = blockIdx.x * 8;
    for (int i = tid; i < SEG; i += 256) { bcnt[i] = 0u; rank_lds[i] = rank[b * SEG + i]; }
    __syncthreads();
    for (int i = tid; i < 8 * W; i += 256) {
        int s = seg[b * HW + y0 * W + i];
        ss[i] = (unsigned char)s;
        out2[b * HW + y0 * W + i] = (float)rank_lds[s];
        lp[i] = (unsigned short)atomicAdd(&bcnt[s], 1u);
    }
    __syncthreads();
    for (int i = tid; i < SEG; i += 256)
        if (bcnt[i]) base_l[i] = (int)atomicAdd(&cursor[b * SEG + i], bcnt[i]);
    __syncthreads();
    for (int i = tid; i < 8 * W; i += 256) {
        int s = ss[i];
        bucket[b * HW + base_l[s] + lp[i]] = (unsigned)(y0 * W + i);
    }
}

// ---------------- k_post: pos [64][HW] f32 -> pos_t [HW][64] bf16, +b1 folded --------
__global__ void k_post(const float* __restrict__ pos, const float* __restrict__ b1,
                       unsigned short* __restrict__ pos_t) {
    const int p = blockIdx.x * 256 + threadIdx.x;
    unsigned d[32];
    #pragma unroll
    for (int c = 0; c < 32; ++c) {
        float v0 = pos[(size_t)(2 * c) * HW + p]     + b1[2 * c];
        float v1 = pos[(size_t)(2 * c + 1) * HW + p] + b1[2 * c + 1];
        d[c] = pack2(v0, v1);
    }
    uint4* op = (uint4*)&pos_t[(size_t)p * 64];
    #pragma unroll
    for (int q = 0; q < 8; ++q) {
        uint4 v = {d[4 * q], d[4 * q + 1], d[4 * q + 2], d[4 * q + 3]};
        op[q] = v;
    }
}

// ---------------- k_wt: pack w1 -> w1t[ky][ks][cg][lane][8] bf16 (frag-contiguous) ----
__global__ void k_wt(const float* __restrict__ w1, unsigned short* __restrict__ w1t) {
    int i = blockIdx.x * 256 + threadIdx.x;
    if (i < 7 * 2 * 2 * 64 * 8) {
        int e = i & 7, lane = (i >> 3) & 63, cg = (i >> 9) & 1, ks = (i >> 10) & 1, ky = i >> 11;
        int kk = ks * 16 + (lane >> 5) * 8 + e;
        int co = cg * 32 + (lane & 31);
        float v = 0.f;
        if (kk < 24) {
            int ci = kk >> 3, kx = kk & 7;
            if (kx < 7) v = w1[((co * 3 + ci) * 7 + ky) * 7 + kx];
        }
        w1t[i] = bfb(v);
    }
}

// ---------------- k_conv_mfma: conv7x7 via bf16 MFMA -> h pixel-major bf16 ------------
// grid (img, 7 x-chunks of 32, 56 y-strips of 4). 4 waves: wave w -> rows
// y0+2*(w>>1)+{0,1}, cg=w&1. Whole 10-row window resident: build, ONE barrier, compute.
// T[slot][quad=kk/8][x][8]: A-frag read AND build write lane-stride-16B (conflict-free).
__launch_bounds__(256, 3)
__global__ void k_conv_mfma(const float* __restrict__ x,
                            const unsigned short* __restrict__ w1t,
                            const unsigned short* __restrict__ pos_t,
                            __hip_bfloat16* __restrict__ h, int b0) {
    __shared__ unsigned short Tl[TSLOTS * 4 * 32 * 8];   // 20480 B

    const int tid = threadIdx.x;
    const int lb  = blockIdx.x;
    const int b   = b0 + lb;
    const int x0  = blockIdx.y * 32;
    const int y0  = blockIdx.z * 4;
    const int lane = tid & 63;
    const int ln31 = lane & 31;
    const int g    = lane >> 5;
    const int wave = tid >> 6;
    const int wr   = wave >> 1;      // row-pair index (0,1)
    const int cg   = wave & 1;       // channel group

    // this wave's cg B-fragments from global (L2-resident, coalesced 16B/lane)
    bf16x8 bfr[7][2];
    #pragma unroll
    for (int ky = 0; ky < 7; ++ky)
        #pragma unroll
        for (int ks = 0; ks < 2; ++ks)
            bfr[ky][ks] = *(const bf16x8*)&w1t[((((ky * 2 + ks) * 2 + cg) * 64) + lane) * 8];

    // zero pad quad 3 (kk 24..31 must stay 0)
    for (int i = tid; i < TSLOTS * 32; i += 256) {
        int slot = i >> 5, xl = i & 31;
        uint4 z = {0, 0, 0, 0};
        *(uint4*)&Tl[((slot * 4 + 3) * 32 + xl) * 8] = z;
    }
    // build rows y0-3 .. y0+6 into slots 0..9 (no ring)
    for (int idx = tid; idx < 96 * TSLOTS; idx += 256) {
        int slot = idx / 96, rem = idx % 96;
        int ci = rem >> 5, xl = rem & 31;
        int r = y0 - 3 + slot;
        uint4 dv = {0, 0, 0, 0};
        if (r >= 0 && r < H) {
            const float* xr = &x[((size_t)(b * CI + ci) * H + r) * W];
            float v[7];
            #pragma unroll
            for (int kx = 0; kx < 7; ++kx) {
                int gx = x0 + xl - 3 + kx;
                v[kx] = (gx >= 0 && gx < W) ? xr[gx] : 0.f;
            }
            dv.x = pack2(v[0], v[1]); dv.y = pack2(v[2], v[3]);
            dv.z = pack2(v[4], v[5]); dv.w = pack2(v[6], 0.f);
        }
        *(uint4*)&Tl[((slot * 4 + ci) * 32 + xl) * 8] = dv;
    }
    __syncthreads();   // the only barrier

    // MFMA: 2 rows x 7 ky x 2 ks (A per row, shared bfr)
    f32x16 c0, c1;
    #pragma unroll
    for (int i = 0; i < 16; ++i) { c0[i] = 0.f; c1[i] = 0.f; }
    const int r0 = y0 + 2 * wr;
    #pragma unroll
    for (int ky = 0; ky < 7; ++ky) {
        const unsigned short* tq0 = &Tl[(2 * wr + ky) * (4 * 32 * 8)];
        const unsigned short* tq1 = &Tl[(2 * wr + ky + 1) * (4 * 32 * 8)];
        #pragma unroll
        for (int ks = 0; ks < 2; ++ks) {
            bf16x8 a0 = *(const bf16x8*)&tq0[((ks * 2 + g) * 32 + ln31) * 8];
            bf16x8 a1 = *(const bf16x8*)&tq1[((ks * 2 + g) * 32 + ln31) * 8];
            c0 = __builtin_amdgcn_mfma_f32_32x32x16_bf16(a0, bfr[ky][ks], c0, 0, 0, 0);
            c1 = __builtin_amdgcn_mfma_f32_32x32x16_bf16(a1, bfr[ky][ks], c1, 0, 0, 0);
        }
    }

    // epilogue: C col(co)=ln31 (+cg*32), row(px)=(reg&3)+8*(reg>>2)+4*g
    #pragma unroll
    for (int reg = 0; reg < 16; ++reg) {
        int pxl = (reg & 3) + 8 * (reg >> 2) + 4 * g;
        int p0 = r0 * W + x0 + pxl;
        int p1 = p0 + W;
        float pv0 = bf2f(pos_t[(size_t)p0 * 64 + cg * 32 + ln31]);
        float pv1 = bf2f(pos_t[(size_t)p1 * 64 + cg * 32 + ln31]);
        h[((size_t)lb * HW + p0) * CO + cg * 32 + ln31] = __float2bfloat16(c0[reg] + pv0);
        h[((size_t)lb * HW + p1) * CO + cg * 32 + ln31] = __float2bfloat16(c1[reg] + pv1);
    }
}

// ---------------- kD: gather-reduce per (image, rank) -> pooled mean ----------------
__global__ void k_gather(const __hip_bfloat16* __restrict__ h,
                         const unsigned* __restrict__ bucket,
                         const int* __restrict__ off_rank,
                         const int* __restrict__ cnt_rank,
                         float* __restrict__ pooled, int b0) {
    const int tid = threadIdx.x;
    const int wave = tid >> 6, lane = tid & 63;
    const int r = blockIdx.x * 4 + wave;
    const int lb = blockIdx.y, b = b0 + lb;
    const int n = cnt_rank[b * SEG + r];
    const int base = off_rank[b * SEG + r];
    const int ps = lane >> 3, cg = lane & 7;

    float acc[8] = {0.f, 0.f, 0.f, 0.f, 0.f, 0.f, 0.f, 0.f};
    const unsigned* bk = &bucket[b * HW + base];
    const int iters = (n + 7) >> 3;
    // 2x unrolled: two independent loads in flight per iteration
    for (int i = 0; i < iters; i += 2) {
        int idx0 = i * 8 + ps;
        int idx1 = idx0 + 8;
        uint4 u0 = {0, 0, 0, 0}, u1 = {0, 0, 0, 0};
        if (idx0 < n) {
            unsigned p = bk[idx0];
            u0 = *(const uint4*)&h[((size_t)lb * HW + p) * CO + cg * 8];
        }
        if (idx1 < n) {
            unsigned p = bk[idx1];
            u1 = *(const uint4*)&h[((size_t)lb * HW + p) * CO + cg * 8];
        }
        const unsigned* w0 = &u0.x;
        const unsigned* w1 = &u1.x;
        #pragma unroll
        for (int j = 0; j < 4; ++j) {
            acc[2 * j]     += __uint_as_float((w0[j] & 0xffffu) << 16)
                            + __uint_as_float((w1[j] & 0xffffu) << 16);
            acc[2 * j + 1] += __uint_as_float(w0[j] & 0xffff0000u)
                            + __uint_as_float(w1[j] & 0xffff0000u);
        }
    }
    #pragma unroll
    for (int m = 8; m < 64; m <<= 1)
        #pragma unroll
        for (int j = 0; j < 8; ++j) acc[j] += __shfl_xor(acc[j], m, 64);

    if (ps == 0) {
        float inv = (n > 0) ? 1.f / (float)n : 0.f;
        float* op = &pooled[((size_t)b * SEG + r) * CO + cg * 8];
        float4 v0 = {acc[0] * inv, acc[1] * inv, acc[2] * inv, acc[3] * inv};
        float4 v1 = {acc[4] * inv, acc[5] * inv, acc[6] * inv, acc[7] * inv};
        *(float4*)&op[0] = v0;
        *(float4*)&op[4] = v1;
    }
}

// ---------------- kE: conv1d k=3 over pooled -> out ----------------
__launch_bounds__(256, 2)
__global__ void k_pool_conv1d(const float* __restrict__ pooledg,
                              const float* __restrict__ w2,
                              const float* __restrict__ b2,
                              float* __restrict__ out0) {
    __shared__ float pooled[CO * PP];
    __shared__ float w2l[192 * (EC + 1)];
    const int tid = threadIdx.x;
    const int b  = blockIdx.y;
    const int e0 = blockIdx.x * EC;

    for (int i = tid; i < SEG * CO; i += 256) {
        int s = i >> 6, c = i & 63;
        pooled[c * PP + s + 1] = pooledg[((size_t)b * SEG + s) * CO + c];
    }
    for (int i = tid; i < CO * 5; i += 256) {
        int c = i / 5, hh = i % 5;
        pooled[c * PP + (hh == 0 ? 0 : 196 + hh)] = 0.f;
    }
    for (int i = tid; i < EC * 192; i += 256) {
        int e = i / 192, k = i % 192;
        w2l[k * (EC + 1) + e] = w2[(size_t)(e0 + e) * 192 + k];
    }
    __syncthreads();

    const int txs = tid & 31;
    const int te  = tid >> 5;
    const int s0  = txs * 7;
    float acc[7][4];
    #pragma unroll
    for (int ss = 0; ss < 7; ++ss)
        #pragma unroll
        for (int ee = 0; ee < 4; ++ee) acc[ss][ee] = b2[e0 + te * 4 + ee];

    if (s0 < SEG) {
        #pragma unroll 4
        for (int c = 0; c < CO; ++c) {
            float pv[9];
            #pragma unroll
            for (int j = 0; j < 9; ++j) pv[j] = pooled[c * PP + s0 + j];
            #pragma unroll
            for (int dk = 0; dk < 3; ++dk) {
                float wv[4];
                #pragma unroll
                for (int ee = 0; ee < 4; ++ee)
                    wv[ee] = w2l[(c * 3 + dk) * (EC + 1) + te * 4 + ee];
                #pragma unroll
                for (int ss = 0; ss < 7; ++ss)
                    #pragma unroll
                    for (int ee = 0; ee < 4; ++ee)
                        acc[ss][ee] = fmaf(pv[ss + dk], wv[ee], acc[ss][ee]);
            }
        }
        #pragma unroll
        for (int ss = 0; ss < 7; ++ss) {
            int s = s0 + ss;
            float* op = &out0[((size_t)(b * SEG + s) * E) + e0 + te * 4];
            float4 v0 = {acc[ss][0], acc[ss][1], acc[ss][2], acc[ss][3]};
            *(float4*)op = v0;
        }
    }
}

extern "C" void kernel_launch(void* const* d_in, const int* in_sizes, int n_in,
                              void* d_out, int out_size, void* d_ws, size_t ws_size,
                              hipStream_t stream) {
    const float* x   = (const float*)d_in[0];
    const int*   seg = (const int*)d_in[1];
    const float* w1  = (const float*)d_in[2];
    const float* b1  = (const float*)d_in[3];
    const float* pos = (const float*)d_in[4];
    const float* w2  = (const float*)d_in[5];
    const float* b2  = (const float*)d_in[6];

    float* out0 = (float*)d_out;                 // [B,196,768]
    float* out2 = out0 + (size_t)B * SEG * E;    // f_segment as float [B,1,224,224]

    int*      present    = (int*)d_ws;                        // B*SEG [zeroed]
    unsigned* counts_raw = (unsigned*)(present + B * SEG);    // B*SEG [zeroed]
    int*      rank       = (int*)(counts_raw + B * SEG);
    int*      off_rank   = rank + B * SEG;
    int*      cnt_rank   = off_rank + B * SEG;
    unsigned* cursor     = (unsigned*)(cnt_rank + B * SEG);
    float*    pooled     = (float*)(cursor + B * SEG);                  // B*SEG*CO
    unsigned* bucket     = (unsigned*)(pooled + (size_t)B * SEG * CO);  // B*HW
    unsigned short* pos_t = (unsigned short*)(bucket + (size_t)B * HW); // HW*64 bf16
    unsigned short* w1t  = pos_t + (size_t)HW * CO;                     // 28672 bf16
    __hip_bfloat16* hbuf = (__hip_bfloat16*)(w1t + 7 * 2 * 2 * 64 * 8);

    hipMemsetAsync(d_ws, 0, (size_t)2 * B * SEG * 4, stream);

    k_post   <<<dim3(HW / 256), 256, 0, stream>>>(pos, b1, pos_t);
    k_wt     <<<dim3(56),       256, 0, stream>>>(w1, w1t);
    k_count  <<<dim3(28, B), 256, 0, stream>>>(seg, present, counts_raw);
    k_offsets<<<dim3(B),     256, 0, stream>>>(present, counts_raw, rank, off_rank, cnt_rank, cursor);
    k_scatter<<<dim3(28, B), 256, 0, stream>>>(seg, rank, cursor, bucket, out2);

    size_t used = (char*)hbuf - (char*)d_ws;
    size_t h_per_img = (size_t)HW * CO * sizeof(__hip_bfloat16);  // 6.42 MB
    size_t avail = (ws_size > used) ? ws_size - used : 0;
    int ipc = (int)(avail / h_per_img);
    if (ipc < 1) ipc = 1;
    if (ipc > B) ipc = B;

    for (int b0 = 0; b0 < B; b0 += ipc) {
        int nb = (b0 + ipc <= B) ? ipc : (B - b0);
        k_conv_mfma<<<dim3(nb, 7, 56), 256, 0, stream>>>(x, w1t, pos_t, hbuf, b0);
        k_gather   <<<dim3(49, nb),    256, 0, stream>>>(hbuf, bucket, off_rank, cnt_rank, pooled, b0);
    }
    k_pool_conv1d<<<dim3(24, B), 256, 0, stream>>>(pooled, w2, b2, out0);
}